// Round 1
// baseline (2731.303 us; speedup 1.0000x reference)
//
#include <hip/hip_runtime.h>
#include <math.h>

#define RANK 64
#define D_DIM 320          // ENT_COMPS * RANK
#define K_DIM 640          // 2 * D_DIM
#define N_ENT 80000
#define B_Q 2000
#define SCALE_F 0.125f     // 1/sqrt(64)
#define EPS_F 1e-9f

// d_out layout (floats):
// scores: [0, 160,000,000)
// reg0:   [160,000,000, +640,000)
// reg1:   [160,640,000, +640,000)
// reg2:   [161,280,000, +640,000)
// reg3:   [161,920,000, +128,000)
// reg4:   [162,048,000, +128,000)
#define OFF_SCORES 0ull
#define OFF_REG0 160000000ull
#define OFF_REG1 160640000ull
#define OFF_REG2 161280000ull
#define OFF_REG3 161920000ull
#define OFF_REG4 162048000ull

// ---------------------------------------------------------------------------
// Prep kernel: one block (64 lanes) per query. Lane k handles rank k.
// Produces X[b][0..639] = [A | Bm] in workspace, plus reg0..reg4 outputs.
// ---------------------------------------------------------------------------
__global__ __launch_bounds__(64) void prep_kernel(
    const int* __restrict__ q,
    const float* __restrict__ ent,       // (80000, 640)
    const float* __restrict__ rrot_t,    // (500, 64, 4)
    const float* __restrict__ rboost_t,  // (500, 64, 4)
    const float* __restrict__ atten_t,   // (500, 320)
    const float* __restrict__ aux_t,     // (500, 2, 320)
    float* __restrict__ X,               // (2000, 640) workspace
    float* __restrict__ out)             // d_out base
{
    int b = blockIdx.x;
    int lane = threadIdx.x;  // 0..63
    int h = q[3 * b + 0];
    int r = q[3 * b + 1];
    int t = q[3 * b + 2];

    const float* eh = ent + (size_t)h * K_DIM;
    const float* et = ent + (size_t)t * K_DIM;

    float4 rv = *(const float4*)(rrot_t + (size_t)r * 256 + lane * 4);
    float4 bv = *(const float4*)(rboost_t + (size_t)r * 256 + lane * 4);

    // lhs_re row for this rank: 5 floats (t, s0..s3)
    const float* xr = eh + lane * 5;
    float x0 = xr[0], x1 = xr[1], x2 = xr[2], x3 = xr[3], x4 = xr[4];

    float rr2 = rv.x * rv.x + rv.y * rv.y + rv.z * rv.z + rv.w * rv.w;
    float rb2 = bv.x * bv.x + bv.y * bv.y + bv.z * bv.z + bv.w * bv.w;

    // --- rotate: normalized quaternion times spatial part ---
    float qinv = 1.0f / sqrtf(rr2 + EPS_F);
    float qw = rv.x * qinv, qx = rv.y * qinv, qy = rv.z * qinv, qz = rv.w * qinv;
    float pw = x1, px = x2, py = x3, pz = x4;
    float rot[5];
    rot[0] = x0;
    rot[1] = qw * pw - qx * px - qy * py - qz * pz;
    rot[2] = qw * px + qx * pw + qy * pz - qz * py;
    rot[3] = qw * py - qx * pz + qy * pw + qz * px;
    rot[4] = qw * pz + qx * py - qy * px + qz * pw;

    // --- boost ---
    float vn2 = fminf(fmaxf(rb2, 0.0f), 0.999f);
    float sq = sqrtf(1.0f - vn2);
    float gamma = 1.0f / sq;
    float gm1 = vn2 / (sq * (1.0f + sq));  // gamma - 1, cancellation-free
    float vs = bv.x * x1 + bv.y * x2 + bv.z * x3 + bv.w * x4;
    float boo[5];
    boo[0] = gamma * (x0 + vs);
    float coef = gamma * x0 + gm1 * vs / (vn2 + EPS_F);
    boo[1] = x1 + coef * bv.x;
    boo[2] = x2 + coef * bv.y;
    boo[3] = x3 + coef * bv.z;
    boo[4] = x4 + coef * bv.w;

    // --- attention logits: dot(atten, rot) and dot(atten, boo) over 320 ---
    const float* at = atten_t + (size_t)r * D_DIM + lane * 5;
    float w0 = at[0] * rot[0] + at[1] * rot[1] + at[2] * rot[2] + at[3] * rot[3] + at[4] * rot[4];
    float w1 = at[0] * boo[0] + at[1] * boo[1] + at[2] * boo[2] + at[3] * boo[3] + at[4] * boo[4];
    #pragma unroll
    for (int off = 32; off; off >>= 1) {
        w0 += __shfl_xor(w0, off);
        w1 += __shfl_xor(w1, off);
    }
    w0 *= SCALE_F;
    w1 *= SCALE_F;
    float mx = fmaxf(w0, w1);
    float e0 = expf(w0 - mx), e1 = expf(w1 - mx);
    float inv = 1.0f / (e0 + e1);
    float wt0 = e0 * inv, wt1 = e1 * inv;

    // --- combine, form A/Bm, write regs ---
    const float* a0p = aux_t + (size_t)r * 640 + lane * 5;
    const float* a1p = a0p + D_DIM;
    float* Xrow = X + (size_t)b * K_DIM;
    float xre[5] = {x0, x1, x2, x3, x4};

    #pragma unroll
    for (int c = 0; c < 5; c++) {
        int d = lane * 5 + c;
        float lhs = wt0 * rot[c] + wt1 * boo[c];
        float im = eh[D_DIM + d];
        float a0 = a0p[c], a1 = a1p[c];
        Xrow[d]         = lhs * a0 - im * a1;
        Xrow[D_DIM + d] = lhs * a1 + im * a0;
        out[OFF_REG0 + (size_t)b * D_DIM + d] = sqrtf(xre[c] * xre[c] + im * im);
        out[OFF_REG1 + (size_t)b * D_DIM + d] = sqrtf(a0 * a0 + a1 * a1);
        float tre = et[d], tim = et[D_DIM + d];
        out[OFF_REG2 + (size_t)b * D_DIM + d] = sqrtf(tre * tre + tim * tim) * (1.0f / 3.0f);
    }
    out[OFF_REG3 + (size_t)b * RANK + lane] = sqrtf(rr2);
    out[OFF_REG4 + (size_t)b * RANK + lane] = sqrtf(rb2);
}

// ---------------------------------------------------------------------------
// GEMM: C (2000 x 80000) = X (2000 x 640) @ E (80000 x 640)^T, fp32.
// BM=64, BN=128, BK=32, 256 threads, 4x8 register tile per thread.
// ---------------------------------------------------------------------------
#define BM 64
#define BN 128
#define BK 32

__global__ __launch_bounds__(256) void gemm_kernel(
    const float* __restrict__ X,
    const float* __restrict__ E,
    float* __restrict__ C)
{
    __shared__ float As[BK][BM + 4];  // [k][m], stride 68 (16B aligned reads)
    __shared__ float Bs[BK][BN + 4];  // [k][n], stride 132

    int m0 = blockIdx.x * BM;
    int n0 = blockIdx.y * BN;
    int tid = threadIdx.x;

    // A loader: 64 rows x 32 k; thread -> row tid&63, kbase (tid>>6)*8 (2 float4)
    int arow = tid & 63;
    int akb = (tid >> 6) * 8;
    // B loader: 128 rows x 32 k; thread -> row tid&127, kbase (tid>>7)*16 (4 float4)
    int brow = tid & 127;
    int bkb = (tid >> 7) * 16;

    int ty = tid >> 4;  // 0..15 -> m sub-rows
    int tx = tid & 15;  // 0..15 -> n sub-cols

    float acc[4][8];
    #pragma unroll
    for (int i = 0; i < 4; i++)
        #pragma unroll
        for (int j = 0; j < 8; j++) acc[i][j] = 0.0f;

    const float4 zero4 = {0.f, 0.f, 0.f, 0.f};
    bool mvalid = (m0 + arow) < B_Q;

    for (int k0 = 0; k0 < K_DIM; k0 += BK) {
        const float* xp = X + (size_t)(m0 + arow) * K_DIM + k0 + akb;
        float4 a0 = mvalid ? *(const float4*)(xp) : zero4;
        float4 a1 = mvalid ? *(const float4*)(xp + 4) : zero4;

        const float* ep = E + (size_t)(n0 + brow) * K_DIM + k0 + bkb;
        float4 b0 = *(const float4*)(ep);
        float4 b1 = *(const float4*)(ep + 4);
        float4 b2 = *(const float4*)(ep + 8);
        float4 b3 = *(const float4*)(ep + 12);

        __syncthreads();  // previous tile's compute done

        As[akb + 0][arow] = a0.x; As[akb + 1][arow] = a0.y;
        As[akb + 2][arow] = a0.z; As[akb + 3][arow] = a0.w;
        As[akb + 4][arow] = a1.x; As[akb + 5][arow] = a1.y;
        As[akb + 6][arow] = a1.z; As[akb + 7][arow] = a1.w;

        Bs[bkb + 0][brow] = b0.x;  Bs[bkb + 1][brow] = b0.y;
        Bs[bkb + 2][brow] = b0.z;  Bs[bkb + 3][brow] = b0.w;
        Bs[bkb + 4][brow] = b1.x;  Bs[bkb + 5][brow] = b1.y;
        Bs[bkb + 6][brow] = b1.z;  Bs[bkb + 7][brow] = b1.w;
        Bs[bkb + 8][brow] = b2.x;  Bs[bkb + 9][brow] = b2.y;
        Bs[bkb + 10][brow] = b2.z; Bs[bkb + 11][brow] = b2.w;
        Bs[bkb + 12][brow] = b3.x; Bs[bkb + 13][brow] = b3.y;
        Bs[bkb + 14][brow] = b3.z; Bs[bkb + 15][brow] = b3.w;

        __syncthreads();

        #pragma unroll 8
        for (int k = 0; k < BK; k++) {
            float4 av  = *(const float4*)&As[k][ty * 4];
            float4 bv0 = *(const float4*)&Bs[k][tx * 4];
            float4 bv1 = *(const float4*)&Bs[k][64 + tx * 4];
            float a_[4] = {av.x, av.y, av.z, av.w};
            float b_[8] = {bv0.x, bv0.y, bv0.z, bv0.w, bv1.x, bv1.y, bv1.z, bv1.w};
            #pragma unroll
            for (int i = 0; i < 4; i++)
                #pragma unroll
                for (int j = 0; j < 8; j++)
                    acc[i][j] = fmaf(a_[i], b_[j], acc[i][j]);
        }
    }

    #pragma unroll
    for (int i = 0; i < 4; i++) {
        int m = m0 + ty * 4 + i;
        if (m < B_Q) {
            float4 c0 = {acc[i][0], acc[i][1], acc[i][2], acc[i][3]};
            float4 c1 = {acc[i][4], acc[i][5], acc[i][6], acc[i][7]};
            float* cp = C + (size_t)m * N_ENT + n0;
            *(float4*)(cp + tx * 4) = c0;
            *(float4*)(cp + 64 + tx * 4) = c1;
        }
    }
}

extern "C" void kernel_launch(void* const* d_in, const int* in_sizes, int n_in,
                              void* d_out, int out_size, void* d_ws, size_t ws_size,
                              hipStream_t stream) {
    const int* queries = (const int*)d_in[0];
    const float* ent = (const float*)d_in[1];
    const float* rrot = (const float*)d_in[2];
    const float* rboost = (const float*)d_in[3];
    const float* atten = (const float*)d_in[4];
    const float* aux = (const float*)d_in[5];
    float* out = (float*)d_out;
    float* X = (float*)d_ws;  // 2000*640 floats = 5.12 MB

    prep_kernel<<<B_Q, 64, 0, stream>>>(queries, ent, rrot, rboost, atten, aux, X, out);

    dim3 grid((B_Q + BM - 1) / BM, N_ENT / BN);  // 32 x 625
    gemm_kernel<<<grid, 256, 0, stream>>>(X, ent, out + OFF_SCORES);
}

// Round 2
// 542.809 us; speedup vs baseline: 5.0318x; 5.0318x over previous
//
#include <hip/hip_runtime.h>
#include <math.h>

#define RANK 64
#define D_DIM 320          // ENT_COMPS * RANK
#define K_DIM 640          // 2 * D_DIM
#define N_ENT 80000
#define B_Q 2000
#define M_PAD 2048         // B_Q padded to multiple of 128
#define SCALE_F 0.125f     // 1/sqrt(64)
#define EPS_F 1e-9f

// d_out layout (floats)
#define OFF_SCORES 0ull
#define OFF_REG0 160000000ull
#define OFF_REG1 160640000ull
#define OFF_REG2 161280000ull
#define OFF_REG3 161920000ull
#define OFF_REG4 162048000ull

typedef __attribute__((ext_vector_type(8))) short short8v;   // 8 bf16 (4 VGPRs)
typedef __attribute__((ext_vector_type(4))) float floatx4;

typedef __attribute__((address_space(1))) const unsigned int gu32;
typedef __attribute__((address_space(3))) unsigned int lu32;

static __device__ __forceinline__ unsigned short f2bf(float f) {
    union { float f; unsigned int u; } a; a.f = f;
    unsigned int u = a.u;
    u += 0x7FFFu + ((u >> 16) & 1u);   // RNE (finite inputs only)
    return (unsigned short)(u >> 16);
}

// ---------------------------------------------------------------------------
// Prep: one 64-lane block per (padded) query row. Lane k handles rank k.
// Writes X[b][0..639] = [A | Bm] in bf16 to ws, plus reg0..reg4 (fp32 exact).
// ---------------------------------------------------------------------------
__global__ __launch_bounds__(64) void prep_kernel(
    const int* __restrict__ q,
    const float* __restrict__ ent,       // (80000, 640)
    const float* __restrict__ rrot_t,    // (500, 64, 4)
    const float* __restrict__ rboost_t,  // (500, 64, 4)
    const float* __restrict__ atten_t,   // (500, 320)
    const float* __restrict__ aux_t,     // (500, 2, 320)
    unsigned short* __restrict__ X,      // (2048, 640) bf16 workspace
    float* __restrict__ out)
{
    int b = blockIdx.x;
    int lane = threadIdx.x;
    unsigned short* Xrow = X + (size_t)b * K_DIM;

    if (b >= B_Q) {  // zero pad rows so MFMA tiles read clean zeros
        #pragma unroll
        for (int c = 0; c < 10; c++) Xrow[lane * 10 + c] = 0;
        return;
    }

    int h = q[3 * b + 0];
    int r = q[3 * b + 1];
    int t = q[3 * b + 2];

    const float* eh = ent + (size_t)h * K_DIM;
    const float* et = ent + (size_t)t * K_DIM;

    float4 rv = *(const float4*)(rrot_t + (size_t)r * 256 + lane * 4);
    float4 bv = *(const float4*)(rboost_t + (size_t)r * 256 + lane * 4);

    const float* xr = eh + lane * 5;
    float x0 = xr[0], x1 = xr[1], x2 = xr[2], x3 = xr[3], x4 = xr[4];

    float rr2 = rv.x * rv.x + rv.y * rv.y + rv.z * rv.z + rv.w * rv.w;
    float rb2 = bv.x * bv.x + bv.y * bv.y + bv.z * bv.z + bv.w * bv.w;

    // rotate
    float qinv = 1.0f / sqrtf(rr2 + EPS_F);
    float qw = rv.x * qinv, qx = rv.y * qinv, qy = rv.z * qinv, qz = rv.w * qinv;
    float pw = x1, px = x2, py = x3, pz = x4;
    float rot[5];
    rot[0] = x0;
    rot[1] = qw * pw - qx * px - qy * py - qz * pz;
    rot[2] = qw * px + qx * pw + qy * pz - qz * py;
    rot[3] = qw * py - qx * pz + qy * pw + qz * px;
    rot[4] = qw * pz + qx * py - qy * px + qz * pw;

    // boost
    float vn2 = fminf(fmaxf(rb2, 0.0f), 0.999f);
    float sq = sqrtf(1.0f - vn2);
    float gamma = 1.0f / sq;
    float gm1 = vn2 / (sq * (1.0f + sq));  // gamma-1 without cancellation
    float vs = bv.x * x1 + bv.y * x2 + bv.z * x3 + bv.w * x4;
    float boo[5];
    boo[0] = gamma * (x0 + vs);
    float coef = gamma * x0 + gm1 * vs / (vn2 + EPS_F);
    boo[1] = x1 + coef * bv.x;
    boo[2] = x2 + coef * bv.y;
    boo[3] = x3 + coef * bv.z;
    boo[4] = x4 + coef * bv.w;

    // attention
    const float* at = atten_t + (size_t)r * D_DIM + lane * 5;
    float w0 = at[0] * rot[0] + at[1] * rot[1] + at[2] * rot[2] + at[3] * rot[3] + at[4] * rot[4];
    float w1 = at[0] * boo[0] + at[1] * boo[1] + at[2] * boo[2] + at[3] * boo[3] + at[4] * boo[4];
    #pragma unroll
    for (int off = 32; off; off >>= 1) {
        w0 += __shfl_xor(w0, off);
        w1 += __shfl_xor(w1, off);
    }
    w0 *= SCALE_F;
    w1 *= SCALE_F;
    float mx = fmaxf(w0, w1);
    float e0 = expf(w0 - mx), e1 = expf(w1 - mx);
    float inv = 1.0f / (e0 + e1);
    float wt0 = e0 * inv, wt1 = e1 * inv;

    const float* a0p = aux_t + (size_t)r * 640 + lane * 5;
    const float* a1p = a0p + D_DIM;
    float xre[5] = {x0, x1, x2, x3, x4};

    #pragma unroll
    for (int c = 0; c < 5; c++) {
        int d = lane * 5 + c;
        float lhs = wt0 * rot[c] + wt1 * boo[c];
        float im = eh[D_DIM + d];
        float a0 = a0p[c], a1 = a1p[c];
        Xrow[d]         = f2bf(lhs * a0 - im * a1);
        Xrow[D_DIM + d] = f2bf(lhs * a1 + im * a0);
        out[OFF_REG0 + (size_t)b * D_DIM + d] = sqrtf(xre[c] * xre[c] + im * im);
        out[OFF_REG1 + (size_t)b * D_DIM + d] = sqrtf(a0 * a0 + a1 * a1);
        float tre = et[d], tim = et[D_DIM + d];
        out[OFF_REG2 + (size_t)b * D_DIM + d] = sqrtf(tre * tre + tim * tim) * (1.0f / 3.0f);
    }
    out[OFF_REG3 + (size_t)b * RANK + lane] = sqrtf(rr2);
    out[OFF_REG4 + (size_t)b * RANK + lane] = sqrtf(rb2);
}

// ---------------------------------------------------------------------------
// E fp32 -> bf16 conversion (80000*640 = 51.2M elements), vectorized.
// ---------------------------------------------------------------------------
__global__ __launch_bounds__(256) void convE_kernel(
    const float* __restrict__ Ef, unsigned short* __restrict__ Eb)
{
    const size_t n4 = (size_t)N_ENT * K_DIM / 4;  // 12.8M float4s
    size_t stride = (size_t)gridDim.x * blockDim.x;
    for (size_t v = (size_t)blockIdx.x * blockDim.x + threadIdx.x; v < n4; v += stride) {
        float4 f = ((const float4*)Ef)[v];
        ushort4 u;
        u.x = f2bf(f.x); u.y = f2bf(f.y); u.z = f2bf(f.z); u.w = f2bf(f.w);
        ((ushort4*)Eb)[v] = u;
    }
}

// ---------------------------------------------------------------------------
// MFMA GEMM: C (2048 x 80000) = X (2048x640) @ E (80000x640)^T, bf16 in, fp32 out.
// m97 structure: 128x128 tile, BK=32, 4 waves, 16x16x32 MFMA, 4x4 frags/wave,
// global_load_lds width=16, 2 barriers per K-step.
// PRE=true : B from pre-converted bf16 (global_load_lds).
// PRE=false: B reg-staged from fp32 with in-flight conversion (ws too small).
// ---------------------------------------------------------------------------
template <bool PRE>
__global__ __launch_bounds__(256) void gemm_mfma(
    const unsigned short* __restrict__ X,   // (2048, 640) bf16
    const float* __restrict__ Ef,           // (80000, 640) fp32
    const unsigned short* __restrict__ Eb,  // (80000, 640) bf16
    float* __restrict__ C)
{
    __shared__ unsigned short As[128 * 32];  // [m][k] row-major, 8 KB
    __shared__ unsigned short Bs[128 * 32];  // [n][k] row-major, 8 KB

    const int tid = threadIdx.x;
    const int lane = tid & 63;
    const int wave = tid >> 6;
    const int wm = wave >> 1, wn = wave & 1;
    const int m0 = blockIdx.x * 128;
    const int n0 = blockIdx.y * 128;

    floatx4 acc[4][4];
    #pragma unroll
    for (int i = 0; i < 4; i++)
        #pragma unroll
        for (int j = 0; j < 4; j++) acc[i][j] = (floatx4)0.0f;

    // staging geometry: 16B/thread/round, 2 rounds cover 128x32 bf16 (8 KB)
    const int srow = tid >> 2;         // 0..63 (round r adds 64)
    const int scol = (tid & 3) * 8;    // bf16 column offset within BK

    // fragment read geometry
    const int fr = lane & 15;          // row (A) / col (B) within 16x16
    const int kb = (lane >> 4) * 8;    // k-octet

    // fallback B staging geometry: thread -> (row = tid>>1, half = tid&1)
    const int brow_f = tid >> 1;
    const int bcol_f = (tid & 1) * 16;

    for (int k0 = 0; k0 < K_DIM; k0 += 32) {
        __syncthreads();  // previous tile's compute done before overwrite

        // --- stage A (always global_load_lds from bf16 X) ---
        #pragma unroll
        for (int r = 0; r < 2; r++) {
            const unsigned short* gp = X + (size_t)(m0 + srow + r * 64) * K_DIM + k0 + scol;
            __builtin_amdgcn_global_load_lds((gu32*)gp, (lu32*)(As + (size_t)(r * 64 + srow) * 32 + scol), 16, 0, 0);
        }

        if (PRE) {
            #pragma unroll
            for (int r = 0; r < 2; r++) {
                const unsigned short* gp = Eb + (size_t)(n0 + srow + r * 64) * K_DIM + k0 + scol;
                __builtin_amdgcn_global_load_lds((gu32*)gp, (lu32*)(Bs + (size_t)(r * 64 + srow) * 32 + scol), 16, 0, 0);
            }
        } else {
            const float* ep = Ef + (size_t)(n0 + brow_f) * K_DIM + k0 + bcol_f;
            float4 f0 = *(const float4*)(ep);
            float4 f1 = *(const float4*)(ep + 4);
            float4 f2 = *(const float4*)(ep + 8);
            float4 f3 = *(const float4*)(ep + 12);
            short8v p0, p1;
            p0[0] = (short)f2bf(f0.x); p0[1] = (short)f2bf(f0.y);
            p0[2] = (short)f2bf(f0.z); p0[3] = (short)f2bf(f0.w);
            p0[4] = (short)f2bf(f1.x); p0[5] = (short)f2bf(f1.y);
            p0[6] = (short)f2bf(f1.z); p0[7] = (short)f2bf(f1.w);
            p1[0] = (short)f2bf(f2.x); p1[1] = (short)f2bf(f2.y);
            p1[2] = (short)f2bf(f2.z); p1[3] = (short)f2bf(f2.w);
            p1[4] = (short)f2bf(f3.x); p1[5] = (short)f2bf(f3.y);
            p1[6] = (short)f2bf(f3.z); p1[7] = (short)f2bf(f3.w);
            *(short8v*)(Bs + (size_t)brow_f * 32 + bcol_f) = p0;
            *(short8v*)(Bs + (size_t)brow_f * 32 + bcol_f + 8) = p1;
        }

        __syncthreads();  // staging visible (vmcnt/lgkmcnt drained by barrier)

        short8v a[4], b[4];
        #pragma unroll
        for (int i = 0; i < 4; i++)
            a[i] = *(const short8v*)(As + (size_t)(wm * 64 + i * 16 + fr) * 32 + kb);
        #pragma unroll
        for (int j = 0; j < 4; j++)
            b[j] = *(const short8v*)(Bs + (size_t)(wn * 64 + j * 16 + fr) * 32 + kb);

        #pragma unroll
        for (int i = 0; i < 4; i++)
            #pragma unroll
            for (int j = 0; j < 4; j++)
                acc[i][j] = __builtin_amdgcn_mfma_f32_16x16x32_bf16(a[i], b[j], acc[i][j], 0, 0, 0);
    }

    // epilogue: C/D layout col=lane&15, row=(lane>>4)*4+reg (m89-verified)
    const int rbase = (lane >> 4) * 4;
    #pragma unroll
    for (int i = 0; i < 4; i++) {
        #pragma unroll
        for (int j = 0; j < 4; j++) {
            int row = m0 + wm * 64 + i * 16 + rbase;
            int col = n0 + wn * 64 + j * 16 + fr;
            #pragma unroll
            for (int r = 0; r < 4; r++) {
                if (row + r < B_Q)
                    C[(size_t)(row + r) * N_ENT + col] = acc[i][j][r];
            }
        }
    }
}

extern "C" void kernel_launch(void* const* d_in, const int* in_sizes, int n_in,
                              void* d_out, int out_size, void* d_ws, size_t ws_size,
                              hipStream_t stream) {
    const int* queries = (const int*)d_in[0];
    const float* ent = (const float*)d_in[1];
    const float* rrot = (const float*)d_in[2];
    const float* rboost = (const float*)d_in[3];
    const float* atten = (const float*)d_in[4];
    const float* aux = (const float*)d_in[5];
    float* out = (float*)d_out;

    unsigned short* X = (unsigned short*)d_ws;            // 2048*640*2 = 2.62 MB
    const size_t offE = (size_t)M_PAD * K_DIM * 2;        // 2,621,440
    const size_t needE = (size_t)N_ENT * K_DIM * 2;       // 102,400,000
    unsigned short* Eb = (unsigned short*)((char*)d_ws + offE);
    bool pre = (ws_size >= offE + needE);

    prep_kernel<<<M_PAD, 64, 0, stream>>>(queries, ent, rrot, rboost, atten, aux, X, out);

    dim3 grid(M_PAD / 128, N_ENT / 128);  // 16 x 625
    if (pre) {
        convE_kernel<<<2048, 256, 0, stream>>>(ent, Eb);
        gemm_mfma<true><<<grid, 256, 0, stream>>>(X, ent, Eb, out + OFF_SCORES);
    } else {
        gemm_mfma<false><<<grid, 256, 0, stream>>>(X, ent, Eb, out + OFF_SCORES);
    }
}

// Round 3
// 389.819 us; speedup vs baseline: 7.0066x; 1.3925x over previous
//
#include <hip/hip_runtime.h>
#include <math.h>

#define RANK 64
#define D_DIM 320          // ENT_COMPS * RANK
#define K_DIM 640          // 2 * D_DIM
#define N_ENT 80000
#define B_Q 2000
#define M_PAD 2048         // B_Q padded to multiple of 256
#define NBLK_N 313         // ceil(80000/256)
#define SCALE_F 0.125f     // 1/sqrt(64)
#define EPS_F 1e-9f

// d_out layout (floats)
#define OFF_SCORES 0ull
#define OFF_REG0 160000000ull
#define OFF_REG1 160640000ull
#define OFF_REG2 161280000ull
#define OFF_REG3 161920000ull
#define OFF_REG4 162048000ull

typedef __attribute__((ext_vector_type(8))) short short8v;   // 8 bf16 (4 VGPRs)
typedef __attribute__((ext_vector_type(4))) float floatx4;

typedef __attribute__((address_space(1))) const unsigned int gu32;
typedef __attribute__((address_space(3))) unsigned int lu32;

static __device__ __forceinline__ unsigned short f2bf(float f) {
    union { float f; unsigned int u; } a; a.f = f;
    unsigned int u = a.u;
    u += 0x7FFFu + ((u >> 16) & 1u);   // RNE (finite inputs only)
    return (unsigned short)(u >> 16);
}

// ---------------------------------------------------------------------------
// Prep: one 64-lane block per (padded) query row. Lane k handles rank k.
// Writes X[b][0..639] = [A | Bm] in bf16 to ws, plus reg0..reg4 (fp32 exact).
// ---------------------------------------------------------------------------
__global__ __launch_bounds__(64) void prep_kernel(
    const int* __restrict__ q,
    const float* __restrict__ ent,       // (80000, 640)
    const float* __restrict__ rrot_t,    // (500, 64, 4)
    const float* __restrict__ rboost_t,  // (500, 64, 4)
    const float* __restrict__ atten_t,   // (500, 320)
    const float* __restrict__ aux_t,     // (500, 2, 320)
    unsigned short* __restrict__ X,      // (2048, 640) bf16 workspace
    float* __restrict__ out)
{
    int b = blockIdx.x;
    int lane = threadIdx.x;
    unsigned short* Xrow = X + (size_t)b * K_DIM;

    if (b >= B_Q) {  // zero pad rows so MFMA tiles read clean zeros
        #pragma unroll
        for (int c = 0; c < 10; c++) Xrow[lane * 10 + c] = 0;
        return;
    }

    int h = q[3 * b + 0];
    int r = q[3 * b + 1];
    int t = q[3 * b + 2];

    const float* eh = ent + (size_t)h * K_DIM;
    const float* et = ent + (size_t)t * K_DIM;

    float4 rv = *(const float4*)(rrot_t + (size_t)r * 256 + lane * 4);
    float4 bv = *(const float4*)(rboost_t + (size_t)r * 256 + lane * 4);

    const float* xr = eh + lane * 5;
    float x0 = xr[0], x1 = xr[1], x2 = xr[2], x3 = xr[3], x4 = xr[4];

    float rr2 = rv.x * rv.x + rv.y * rv.y + rv.z * rv.z + rv.w * rv.w;
    float rb2 = bv.x * bv.x + bv.y * bv.y + bv.z * bv.z + bv.w * bv.w;

    // rotate
    float qinv = 1.0f / sqrtf(rr2 + EPS_F);
    float qw = rv.x * qinv, qx = rv.y * qinv, qy = rv.z * qinv, qz = rv.w * qinv;
    float pw = x1, px = x2, py = x3, pz = x4;
    float rot[5];
    rot[0] = x0;
    rot[1] = qw * pw - qx * px - qy * py - qz * pz;
    rot[2] = qw * px + qx * pw + qy * pz - qz * py;
    rot[3] = qw * py - qx * pz + qy * pw + qz * px;
    rot[4] = qw * pz + qx * py - qy * px + qz * pw;

    // boost
    float vn2 = fminf(fmaxf(rb2, 0.0f), 0.999f);
    float sq = sqrtf(1.0f - vn2);
    float gamma = 1.0f / sq;
    float gm1 = vn2 / (sq * (1.0f + sq));  // gamma-1 without cancellation
    float vs = bv.x * x1 + bv.y * x2 + bv.z * x3 + bv.w * x4;
    float boo[5];
    boo[0] = gamma * (x0 + vs);
    float coef = gamma * x0 + gm1 * vs / (vn2 + EPS_F);
    boo[1] = x1 + coef * bv.x;
    boo[2] = x2 + coef * bv.y;
    boo[3] = x3 + coef * bv.z;
    boo[4] = x4 + coef * bv.w;

    // attention
    const float* at = atten_t + (size_t)r * D_DIM + lane * 5;
    float w0 = at[0] * rot[0] + at[1] * rot[1] + at[2] * rot[2] + at[3] * rot[3] + at[4] * rot[4];
    float w1 = at[0] * boo[0] + at[1] * boo[1] + at[2] * boo[2] + at[3] * boo[3] + at[4] * boo[4];
    #pragma unroll
    for (int off = 32; off; off >>= 1) {
        w0 += __shfl_xor(w0, off);
        w1 += __shfl_xor(w1, off);
    }
    w0 *= SCALE_F;
    w1 *= SCALE_F;
    float mx = fmaxf(w0, w1);
    float e0 = expf(w0 - mx), e1 = expf(w1 - mx);
    float inv = 1.0f / (e0 + e1);
    float wt0 = e0 * inv, wt1 = e1 * inv;

    const float* a0p = aux_t + (size_t)r * 640 + lane * 5;
    const float* a1p = a0p + D_DIM;
    float xre[5] = {x0, x1, x2, x3, x4};

    #pragma unroll
    for (int c = 0; c < 5; c++) {
        int d = lane * 5 + c;
        float lhs = wt0 * rot[c] + wt1 * boo[c];
        float im = eh[D_DIM + d];
        float a0 = a0p[c], a1 = a1p[c];
        Xrow[d]         = f2bf(lhs * a0 - im * a1);
        Xrow[D_DIM + d] = f2bf(lhs * a1 + im * a0);
        out[OFF_REG0 + (size_t)b * D_DIM + d] = sqrtf(xre[c] * xre[c] + im * im);
        out[OFF_REG1 + (size_t)b * D_DIM + d] = sqrtf(a0 * a0 + a1 * a1);
        float tre = et[d], tim = et[D_DIM + d];
        out[OFF_REG2 + (size_t)b * D_DIM + d] = sqrtf(tre * tre + tim * tim) * (1.0f / 3.0f);
    }
    out[OFF_REG3 + (size_t)b * RANK + lane] = sqrtf(rr2);
    out[OFF_REG4 + (size_t)b * RANK + lane] = sqrtf(rb2);
}

// ---------------------------------------------------------------------------
// E fp32 -> bf16 conversion (80000*640 elements), vectorized.
// ---------------------------------------------------------------------------
__global__ __launch_bounds__(256) void convE_kernel(
    const float* __restrict__ Ef, unsigned short* __restrict__ Eb)
{
    const size_t n4 = (size_t)N_ENT * K_DIM / 4;
    size_t stride = (size_t)gridDim.x * blockDim.x;
    for (size_t v = (size_t)blockIdx.x * blockDim.x + threadIdx.x; v < n4; v += stride) {
        float4 f = ((const float4*)Ef)[v];
        ushort4 u;
        u.x = f2bf(f.x); u.y = f2bf(f.y); u.z = f2bf(f.z); u.w = f2bf(f.w);
        ((ushort4*)Eb)[v] = u;
    }
}

// ---------------------------------------------------------------------------
// MFMA GEMM, 256x256 tile, BK=64, 8 waves (2M x 4N), single-barrier pipelined
// double-buffer (guide T3-lite recipe), XOR-swizzled LDS (rule 21: linear
// dest + pre-swizzled global source + swizzled ds_read), XCD mapping with
// m-block == XCD so E streams through HBM once.
// ---------------------------------------------------------------------------
__global__ __launch_bounds__(512, 2) void gemm256(
    const unsigned short* __restrict__ X,   // (2048, 640) bf16
    const unsigned short* __restrict__ Eb,  // (80000, 640) bf16
    float* __restrict__ C)
{
    // LDS: buf b: A at b*16384 shorts (32KB), B at 32768 + b*16384. Total 128KB.
    __shared__ unsigned short lds[65536];

    const int tid = threadIdx.x;
    const int lane = tid & 63;
    const int wid = tid >> 6;
    const int wm = wid >> 2;          // 0..1  (128-row half)
    const int wn = wid & 3;           // 0..3  (64-col quarter)

    // XCD-aware swizzle: 2504 blocks, chunk of 313 per XCD -> m-block == XCD.
    int bid = blockIdx.x;
    int swz = (bid & 7) * NBLK_N + (bid >> 3);
    const int m0 = (swz / NBLK_N) * 256;
    const int n0 = (swz % NBLK_N) * 256;

    const int fr = lane & 15;         // row within 16x16 frag
    const int kq = lane >> 4;         // k-octet quarter

    floatx4 acc[8][4];
    #pragma unroll
    for (int i = 0; i < 8; i++)
        #pragma unroll
        for (int j = 0; j < 4; j++) acc[i][j] = (floatx4)0.0f;

    // Staging geometry: 512 thr x 16B = 8KB/round; 4 rounds per 32KB matrix.
    // LDS dest is LINEAR (wave-uniform base + lane*16B — verified lane-linear);
    // global source column-block is pre-swizzled: blk_g = blk_l ^ (row & 7).
    const int srow = tid >> 3;                               // 0..63 (+64/round)
    const int scol_sw = ((tid & 7) ^ ((tid >> 3) & 7)) * 8;  // shorts (row&7 == (tid>>3)&7)
    const int sdst = srow * 64 + (tid & 7) * 8;              // shorts (+ r*4096)

    auto stage = [&](int buf, int kt) {
        const int k0 = kt * 64;
        const int Ab = buf * 16384;
        const int Bb = 32768 + buf * 16384;
        #pragma unroll
        for (int r = 0; r < 4; r++) {
            const unsigned short* ga = X + (size_t)(m0 + r * 64 + srow) * K_DIM + k0 + scol_sw;
            __builtin_amdgcn_global_load_lds((gu32*)ga, (lu32*)&lds[Ab + r * 4096 + sdst], 16, 0, 0);
        }
        #pragma unroll
        for (int r = 0; r < 4; r++) {
            int grow = n0 + r * 64 + srow;
            if (grow > N_ENT - 1) grow = N_ENT - 1;   // tail clamp (finite garbage, never stored)
            const unsigned short* gb = Eb + (size_t)grow * K_DIM + k0 + scol_sw;
            __builtin_amdgcn_global_load_lds((gu32*)gb, (lu32*)&lds[Bb + r * 4096 + sdst], 16, 0, 0);
        }
    };

    stage(0, 0);
    __syncthreads();   // compiler emits vmcnt(0) before s_barrier -> tile 0 landed

    int buf = 0;
    for (int kt = 0; kt < K_DIM / 64; kt++) {
        if (kt < K_DIM / 64 - 1) stage(buf ^ 1, kt + 1);   // prefetch next tile

        const int Ab = buf * 16384;
        const int Bb = 32768 + buf * 16384;
        #pragma unroll
        for (int ks = 0; ks < 2; ks++) {
            short8v a[8], b[4];
            const int swk = ((ks * 4 + kq) ^ (fr & 7)) * 8;  // swizzled k-block (shorts)
            #pragma unroll
            for (int i = 0; i < 8; i++) {
                int row = wm * 128 + i * 16 + fr;
                a[i] = *(const short8v*)&lds[Ab + row * 64 + swk];
            }
            #pragma unroll
            for (int j = 0; j < 4; j++) {
                int row = wn * 64 + j * 16 + fr;
                b[j] = *(const short8v*)&lds[Bb + row * 64 + swk];
            }
            #pragma unroll
            for (int i = 0; i < 8; i++)
                #pragma unroll
                for (int j = 0; j < 4; j++)
                    acc[i][j] = __builtin_amdgcn_mfma_f32_16x16x32_bf16(a[i], b[j], acc[i][j], 0, 0, 0);
        }
        __syncthreads();  // drains vmcnt(0)+lgkmcnt(0) AFTER the MFMAs
        buf ^= 1;
    }

    // Epilogue: C/D layout col=lane&15, row=(lane>>4)*4+reg (m89-verified).
    const int rb = kq * 4;
    #pragma unroll
    for (int i = 0; i < 8; i++) {
        #pragma unroll
        for (int j = 0; j < 4; j++) {
            int row = m0 + wm * 128 + i * 16 + rb;
            int col = n0 + wn * 64 + j * 16 + fr;
            if (col < N_ENT) {
                #pragma unroll
                for (int r = 0; r < 4; r++) {
                    if (row + r < B_Q)
                        C[(size_t)(row + r) * N_ENT + col] = acc[i][j][r];
                }
            }
        }
    }
}

// ---------------------------------------------------------------------------
// Fallback GEMM (R2-verified, 128x128 m97 structure) for ws-too-small case:
// B reg-staged from fp32 with in-flight conversion.
// ---------------------------------------------------------------------------
__global__ __launch_bounds__(256) void gemm_mfma_fb(
    const unsigned short* __restrict__ X,
    const float* __restrict__ Ef,
    float* __restrict__ C)
{
    __shared__ unsigned short As[128 * 32];
    __shared__ unsigned short Bs[128 * 32];

    const int tid = threadIdx.x;
    const int lane = tid & 63;
    const int wave = tid >> 6;
    const int wm = wave >> 1, wn = wave & 1;
    const int m0 = blockIdx.x * 128;
    const int n0 = blockIdx.y * 128;

    floatx4 acc[4][4];
    #pragma unroll
    for (int i = 0; i < 4; i++)
        #pragma unroll
        for (int j = 0; j < 4; j++) acc[i][j] = (floatx4)0.0f;

    const int srow = tid >> 2;
    const int scol = (tid & 3) * 8;
    const int fr = lane & 15;
    const int kb = (lane >> 4) * 8;
    const int brow_f = tid >> 1;
    const int bcol_f = (tid & 1) * 16;

    for (int k0 = 0; k0 < K_DIM; k0 += 32) {
        __syncthreads();
        #pragma unroll
        for (int r = 0; r < 2; r++) {
            const unsigned short* gp = X + (size_t)(m0 + srow + r * 64) * K_DIM + k0 + scol;
            __builtin_amdgcn_global_load_lds((gu32*)gp, (lu32*)(As + (size_t)(r * 64 + srow) * 32 + scol), 16, 0, 0);
        }
        {
            const float* ep = Ef + (size_t)(n0 + brow_f) * K_DIM + k0 + bcol_f;
            float4 f0 = *(const float4*)(ep);
            float4 f1 = *(const float4*)(ep + 4);
            float4 f2 = *(const float4*)(ep + 8);
            float4 f3 = *(const float4*)(ep + 12);
            short8v p0, p1;
            p0[0] = (short)f2bf(f0.x); p0[1] = (short)f2bf(f0.y);
            p0[2] = (short)f2bf(f0.z); p0[3] = (short)f2bf(f0.w);
            p0[4] = (short)f2bf(f1.x); p0[5] = (short)f2bf(f1.y);
            p0[6] = (short)f2bf(f1.z); p0[7] = (short)f2bf(f1.w);
            p1[0] = (short)f2bf(f2.x); p1[1] = (short)f2bf(f2.y);
            p1[2] = (short)f2bf(f2.z); p1[3] = (short)f2bf(f2.w);
            p1[4] = (short)f2bf(f3.x); p1[5] = (short)f2bf(f3.y);
            p1[6] = (short)f2bf(f3.z); p1[7] = (short)f2bf(f3.w);
            *(short8v*)(Bs + (size_t)brow_f * 32 + bcol_f) = p0;
            *(short8v*)(Bs + (size_t)brow_f * 32 + bcol_f + 8) = p1;
        }
        __syncthreads();

        short8v a[4], b[4];
        #pragma unroll
        for (int i = 0; i < 4; i++)
            a[i] = *(const short8v*)(As + (size_t)(wm * 64 + i * 16 + fr) * 32 + kb);
        #pragma unroll
        for (int j = 0; j < 4; j++)
            b[j] = *(const short8v*)(Bs + (size_t)(wn * 64 + j * 16 + fr) * 32 + kb);

        #pragma unroll
        for (int i = 0; i < 4; i++)
            #pragma unroll
            for (int j = 0; j < 4; j++)
                acc[i][j] = __builtin_amdgcn_mfma_f32_16x16x32_bf16(a[i], b[j], acc[i][j], 0, 0, 0);
    }

    const int rbase = (lane >> 4) * 4;
    #pragma unroll
    for (int i = 0; i < 4; i++) {
        #pragma unroll
        for (int j = 0; j < 4; j++) {
            int row = m0 + wm * 64 + i * 16 + rbase;
            int col = n0 + wn * 64 + j * 16 + fr;
            #pragma unroll
            for (int r = 0; r < 4; r++) {
                if (row + r < B_Q)
                    C[(size_t)(row + r) * N_ENT + col] = acc[i][j][r];
            }
        }
    }
}

extern "C" void kernel_launch(void* const* d_in, const int* in_sizes, int n_in,
                              void* d_out, int out_size, void* d_ws, size_t ws_size,
                              hipStream_t stream) {
    const int* queries = (const int*)d_in[0];
    const float* ent = (const float*)d_in[1];
    const float* rrot = (const float*)d_in[2];
    const float* rboost = (const float*)d_in[3];
    const float* atten = (const float*)d_in[4];
    const float* aux = (const float*)d_in[5];
    float* out = (float*)d_out;

    unsigned short* X = (unsigned short*)d_ws;            // 2048*640*2 = 2.62 MB
    const size_t offE = (size_t)M_PAD * K_DIM * 2;
    const size_t needE = (size_t)N_ENT * K_DIM * 2;       // 102.4 MB
    unsigned short* Eb = (unsigned short*)((char*)d_ws + offE);
    bool pre = (ws_size >= offE + needE);

    prep_kernel<<<M_PAD, 64, 0, stream>>>(queries, ent, rrot, rboost, atten, aux, X, out);

    if (pre) {
        convE_kernel<<<2048, 256, 0, stream>>>(ent, Eb);
        gemm256<<<8 * NBLK_N, 512, 0, stream>>>(X, Eb, out + OFF_SCORES);
    } else {
        dim3 grid(M_PAD / 128, N_ENT / 128);
        gemm_mfma_fb<<<grid, 256, 0, stream>>>(X, ent, out + OFF_SCORES);
    }
}